// Round 5
// baseline (193.105 us; speedup 1.0000x reference)
//
#include <hip/hip_runtime.h>
#include <hip/hip_bf16.h>

#define HDIM 256
#define HPDIM 128

typedef short bf8 __attribute__((ext_vector_type(8)));   // 8 bf16 in 4 VGPRs
typedef float f32x4 __attribute__((ext_vector_type(4)));

__device__ inline unsigned pkbf2(float a, float b) {
  float2 f; f.x = a; f.y = b;
  __hip_bfloat162 h = __float22bfloat162_rn(f);          // v_cvt_pk_bf16_f32 (RNE)
  unsigned u; __builtin_memcpy(&u, &h, 4); return u;
}
__device__ inline unsigned short bfbits(float v) {
  __hip_bfloat16 h = __float2bfloat16(v);
  unsigned short u; __builtin_memcpy(&u, &h, 2); return u;
}
__device__ inline uint4 pack8u(float4 a, float4 b) {
  uint4 r;
  r.x = pkbf2(a.x, a.y); r.y = pkbf2(a.z, a.w);
  r.z = pkbf2(b.x, b.y); r.w = pkbf2(b.z, b.w);
  return r;
}
__device__ inline float fast_tanh(float x) {
  float t = __expf(2.0f * x);                 // inf/0 at extremes -> +-1 exact
  return 1.0f - 2.0f * __builtin_amdgcn_rcpf(t + 1.0f);
}

// ---------------- Kernel A: front MLP -> x3 (bf16)  +  msg transpose ------
// blocks 0..63: MLP, 16 b each (weights staged coalesced into LDS).
// blocks 64..79: transpose msg [b][h] -> msgT [h][b], 64 b each.
__global__ __launch_bounds__(256) void k_pre(
    const float* __restrict__ h0, const float* __restrict__ htv,
    const float* __restrict__ cp, const float* __restrict__ msg,
    const float* __restrict__ w1, const float* __restrict__ w2,
    const float* __restrict__ w3,
    short* __restrict__ x3bf, float* __restrict__ msgT) {
  __shared__ char lds[81920];
  const int t = threadIdx.x, wave = t >> 6, lane = t & 63;

  if (blockIdx.x >= 64) {
    // ---- msg transpose: tile 64 b x 256 h through padded LDS ----
    float* T = (float*)lds;                   // [64][257] f32
    const int b0 = (blockIdx.x - 64) * 64;
    #pragma unroll 4
    for (int it = 0; it < 16; ++it) {
      int flat = it * 1024 + t * 4;
      int row = flat >> 8, col = flat & 255;
      float4 v = *(const float4*)(msg + (b0 + row) * HDIM + col);
      T[row*257 + col]   = v.x; T[row*257 + col+1] = v.y;
      T[row*257 + col+2] = v.z; T[row*257 + col+3] = v.w;
    }
    __syncthreads();
    const int bloc = t & 63, hbase = wave * 64;
    #pragma unroll 8
    for (int hh = 0; hh < 64; ++hh) {
      int h = hbase + hh;
      msgT[h*1024 + b0 + bloc] = T[bloc*257 + h];
    }
    return;
  }

  char* wbuf = lds;             // 64KB weight buffer (reused per layer)
  char* hbuf = lds + 65536;     // 16 x 256 bf16, swizzled
  char* xa   = lds + 73728;     // 16 x 128 bf16, swizzled
  char* xb   = lds + 77824;
  const int r16 = lane & 15, quad = lane >> 4;
  const int b0 = blockIdx.x * 16;
  const float cc = fminf(fmaxf(cp[0], 0.f), 1.f);

  // stage h = cc*h0+(1-cc)*ht (16x256 f32)
  #pragma unroll
  for (int it = 0; it < 2; ++it) {
    int flat = it * 2048 + t * 8;
    int row = flat >> 8, col = flat & 255, kb = col >> 3;
    int gi = (b0 + row) * HDIM + col;
    float4 a = *(const float4*)(h0 + gi);
    float4 b = *(const float4*)(htv + gi);
    float4 va, vb;
    va.x = cc*a.x + (1.f-cc)*b.x; va.y = cc*a.y + (1.f-cc)*b.y;
    va.z = cc*a.z + (1.f-cc)*b.z; va.w = cc*a.w + (1.f-cc)*b.w;
    a = *(const float4*)(h0 + gi + 4); b = *(const float4*)(htv + gi + 4);
    vb.x = cc*a.x + (1.f-cc)*b.x; vb.y = cc*a.y + (1.f-cc)*b.y;
    vb.z = cc*a.z + (1.f-cc)*b.z; vb.w = cc*a.w + (1.f-cc)*b.w;
    *(uint4*)(hbuf + row*512 + ((kb ^ (row & 7)) << 4)) = pack8u(va, vb);
  }
  // stage w1 (128x256 f32)
  #pragma unroll 4
  for (int it = 0; it < 16; ++it) {
    int flat = it * 2048 + t * 8;
    int row = flat >> 8, col = flat & 255, kb = col >> 3;
    float4 a = *(const float4*)(w1 + flat);
    float4 b = *(const float4*)(w1 + flat + 4);
    *(uint4*)(wbuf + row*512 + ((kb ^ (row & 7)) << 4)) = pack8u(a, b);
  }
  __syncthreads();

  // layer 1: [16 x 256] @ w1^T -> xa (tanh)
  {
    f32x4 acc[2] = {};
    #pragma unroll
    for (int ks = 0; ks < 8; ++ks) {
      bf8 af = *(bf8*)(hbuf + r16*512 + (((ks*4 + quad) ^ (r16 & 7)) << 4));
      #pragma unroll
      for (int nt = 0; nt < 2; ++nt) {
        int p = wave*32 + nt*16 + r16;
        bf8 bf_ = *(bf8*)(wbuf + p*512 + (((ks*4 + quad) ^ (p & 7)) << 4));
        acc[nt] = __builtin_amdgcn_mfma_f32_16x16x32_bf16(af, bf_, acc[nt], 0, 0, 0);
      }
    }
    #pragma unroll
    for (int nt = 0; nt < 2; ++nt)
      #pragma unroll
      for (int i = 0; i < 4; ++i) {
        int row = quad*4 + i, col = wave*32 + nt*16 + r16;
        *(unsigned short*)(xa + row*256 + (((col >> 3) ^ (row & 7)) << 4) + ((col & 7) << 1))
            = bfbits(fast_tanh(acc[nt][i]));
      }
  }
  __syncthreads();
  // stage w2 (128x128)
  #pragma unroll 4
  for (int it = 0; it < 8; ++it) {
    int flat = it * 2048 + t * 8;
    int row = flat >> 7, kb = t & 15;
    float4 a = *(const float4*)(w2 + flat);
    float4 b = *(const float4*)(w2 + flat + 4);
    *(uint4*)(wbuf + row*256 + ((kb ^ (row & 7)) << 4)) = pack8u(a, b);
  }
  __syncthreads();
  // layer 2: xa @ w2^T -> xb
  {
    f32x4 acc[2] = {};
    #pragma unroll
    for (int ks = 0; ks < 4; ++ks) {
      bf8 af = *(bf8*)(xa + r16*256 + (((ks*4 + quad) ^ (r16 & 7)) << 4));
      #pragma unroll
      for (int nt = 0; nt < 2; ++nt) {
        int p = wave*32 + nt*16 + r16;
        bf8 bf_ = *(bf8*)(wbuf + p*256 + (((ks*4 + quad) ^ (p & 7)) << 4));
        acc[nt] = __builtin_amdgcn_mfma_f32_16x16x32_bf16(af, bf_, acc[nt], 0, 0, 0);
      }
    }
    #pragma unroll
    for (int nt = 0; nt < 2; ++nt)
      #pragma unroll
      for (int i = 0; i < 4; ++i) {
        int row = quad*4 + i, col = wave*32 + nt*16 + r16;
        *(unsigned short*)(xb + row*256 + (((col >> 3) ^ (row & 7)) << 4) + ((col & 7) << 1))
            = bfbits(fast_tanh(acc[nt][i]));
      }
  }
  __syncthreads();
  // stage w3 (128x128)
  #pragma unroll 4
  for (int it = 0; it < 8; ++it) {
    int flat = it * 2048 + t * 8;
    int row = flat >> 7, kb = t & 15;
    float4 a = *(const float4*)(w3 + flat);
    float4 b = *(const float4*)(w3 + flat + 4);
    *(uint4*)(wbuf + row*256 + ((kb ^ (row & 7)) << 4)) = pack8u(a, b);
  }
  __syncthreads();
  // layer 3: xb @ w3^T -> xa
  {
    f32x4 acc[2] = {};
    #pragma unroll
    for (int ks = 0; ks < 4; ++ks) {
      bf8 af = *(bf8*)(xb + r16*256 + (((ks*4 + quad) ^ (r16 & 7)) << 4));
      #pragma unroll
      for (int nt = 0; nt < 2; ++nt) {
        int p = wave*32 + nt*16 + r16;
        bf8 bf_ = *(bf8*)(wbuf + p*256 + (((ks*4 + quad) ^ (p & 7)) << 4));
        acc[nt] = __builtin_amdgcn_mfma_f32_16x16x32_bf16(af, bf_, acc[nt], 0, 0, 0);
      }
    }
    #pragma unroll
    for (int nt = 0; nt < 2; ++nt)
      #pragma unroll
      for (int i = 0; i < 4; ++i) {
        int row = quad*4 + i, col = wave*32 + nt*16 + r16;
        *(unsigned short*)(xa + row*256 + (((col >> 3) ^ (row & 7)) << 4) + ((col & 7) << 1))
            = bfbits(fast_tanh(acc[nt][i]));
      }
  }
  __syncthreads();
  // dump xa -> x3bf, coalesced uint4
  {
    int row = t >> 4, kb = t & 15;
    uint4 d = *(uint4*)(xa + row*256 + ((kb ^ (row & 7)) << 4));
    *(uint4*)(x3bf + (b0 + row)*HPDIM + kb*8) = d;
  }
}

// ---------------- Kernel B/C: fused hypernetwork GEMM --------------------
// PHASE 0: g1T[kcol,b] = tanh( sum_h msgT[h,b] * (fc4[kcol*256+h,:] . x3[b,:]) )
// PHASE 1: out[b,kcol] =       sum_k g1T[k,b]  * (fc4[65536+kcol*256+k,:] . x3[b,:])
// Grid (256 kcol, 4 y); block = 256 b, wave owns 64 b. Slab staged in two
// 128-row halves (32 KB LDS -> 4 blocks/CU resident). wvecT loads are
// dense 64-B segments (transposed layout).
template<int PHASE>
__global__ __launch_bounds__(256, 4) void k_hyper(
    const short* __restrict__ x3bf, const float* __restrict__ wvecT,
    const float* __restrict__ fc4, float* __restrict__ outp) {
  __shared__ char lds[32768];          // 128 rows x 128 bf16, xor-swizzled
  const int kcol = blockIdx.x;
  const int t = threadIdx.x, wave = t >> 6, lane = t & 63;
  const int r16 = lane & 15, quad = lane >> 4;
  const int bw = blockIdx.y * 256 + wave * 64;

  // x3 B-fragments (held whole kernel): B[k=quad*8+j][n=r16], n = b-local
  bf8 xf[4][4];
  #pragma unroll
  for (int nt = 0; nt < 4; ++nt)
    #pragma unroll
    for (int ks = 0; ks < 4; ++ks)
      xf[nt][ks] = *(const bf8*)(x3bf + (bw + nt*16 + r16)*HPDIM + ks*32 + quad*8);

  const float* src = fc4 + ((size_t)(PHASE ? 65536 : 0) + (size_t)kcol * 256) * HPDIM;
  float gacc[4] = {0.f, 0.f, 0.f, 0.f};

  #pragma unroll 1
  for (int half = 0; half < 2; ++half) {
    // stage 128 rows x 128 f32 -> bf16 LDS, one ds_write_b128/thread/iter
    #pragma unroll
    for (int it = 0; it < 8; ++it) {
      int flat = it * 2048 + t * 8;
      int row = flat >> 7, kb = t & 15;
      float4 a = *(const float4*)(src + half*16384 + flat);
      float4 b = *(const float4*)(src + half*16384 + flat + 4);
      *(uint4*)(lds + row*256 + ((kb ^ (row & 7)) << 4)) = pack8u(a, b);
    }
    __syncthreads();

    #pragma unroll 2
    for (int ht = 0; ht < 8; ++ht) {
      const int row = ht*16 + r16;
      bf8 af[4];
      #pragma unroll
      for (int ks = 0; ks < 4; ++ks)
        af[ks] = *(bf8*)(lds + row*256 + (((ks*4 + quad) ^ (row & 7)) << 4));
      const int hbase = half*128 + ht*16 + quad*4;
      #pragma unroll
      for (int nt = 0; nt < 4; ++nt) {
        f32x4 acc = {};
        #pragma unroll
        for (int ks = 0; ks < 4; ++ks)
          acc = __builtin_amdgcn_mfma_f32_16x16x32_bf16(af[ks], xf[nt][ks], acc, 0, 0, 0);
        const float* wp = wvecT + (size_t)hbase*1024 + bw + nt*16 + r16;
        gacc[nt] += acc[0]*wp[0] + acc[1]*wp[1024] + acc[2]*wp[2048] + acc[3]*wp[3072];
      }
    }
    __syncthreads();                         // slab reads done before restage
  }

  #pragma unroll
  for (int nt = 0; nt < 4; ++nt) {
    float v = gacc[nt];
    v += __shfl_xor(v, 16);
    v += __shfl_xor(v, 32);
    if (quad == 0) {
      int b = bw + nt*16 + r16;
      if (PHASE == 0) outp[kcol*1024 + b] = fast_tanh(v);   // g1T[k][b], coalesced
      else            outp[b*HDIM + kcol] = v;              // out[b][o]
    }
  }
}

extern "C" void kernel_launch(void* const* d_in, const int* in_sizes, int n_in,
                              void* d_out, int out_size, void* d_ws, size_t ws_size,
                              hipStream_t stream) {
  const float* h0  = (const float*)d_in[0];
  const float* htt = (const float*)d_in[1];
  const float* msg = (const float*)d_in[2];
  const float* c   = (const float*)d_in[3];
  const float* w1  = (const float*)d_in[4];
  const float* w2  = (const float*)d_in[5];
  const float* w3  = (const float*)d_in[6];
  const float* w4  = (const float*)d_in[7];
  float* out = (float*)d_out;

  short* x3bf = (short*)d_ws;                            // 256 KB
  float* g1T  = (float*)((char*)d_ws + 262144);          // [256][1024] f32, 1 MB
  float* msgT = (float*)((char*)d_ws + 262144 + 1048576);// [256][1024] f32, 1 MB

  k_pre<<<dim3(80), dim3(256), 0, stream>>>(h0, htt, c, msg, w1, w2, w3, x3bf, msgT);
  k_hyper<0><<<dim3(256, 4), dim3(256), 0, stream>>>(x3bf, msgT, w4, g1T);
  k_hyper<1><<<dim3(256, 4), dim3(256), 0, stream>>>(x3bf, g1T, w4, out);
}

// Round 6
// 181.780 us; speedup vs baseline: 1.0623x; 1.0623x over previous
//
#include <hip/hip_runtime.h>
#include <hip/hip_bf16.h>

#define HDIM 256
#define HPDIM 128

typedef short bf8 __attribute__((ext_vector_type(8)));   // 8 bf16 in 4 VGPRs
typedef float f32x4 __attribute__((ext_vector_type(4)));

__device__ inline unsigned pkbf2(float a, float b) {
  float2 f; f.x = a; f.y = b;
  __hip_bfloat162 h = __float22bfloat162_rn(f);          // v_cvt_pk_bf16_f32 (RNE)
  unsigned u; __builtin_memcpy(&u, &h, 4); return u;
}
__device__ inline unsigned short bfbits(float v) {
  __hip_bfloat16 h = __float2bfloat16(v);
  unsigned short u; __builtin_memcpy(&u, &h, 2); return u;
}
__device__ inline uint4 pack8u(float4 a, float4 b) {
  uint4 r;
  r.x = pkbf2(a.x, a.y); r.y = pkbf2(a.z, a.w);
  r.z = pkbf2(b.x, b.y); r.w = pkbf2(b.z, b.w);
  return r;
}
__device__ inline float fast_tanh(float x) {
  float t = __expf(2.0f * x);                 // inf/0 at extremes -> +-1 exact
  return 1.0f - 2.0f * __builtin_amdgcn_rcpf(t + 1.0f);
}

// ---------------- Kernel 0: format weights + transpose msg ----------------
// blocks 0..31: w1/w2/w3 -> bf16 MFMA-B-fragment order:
//   wf[((P*Kt + ks)*64 + lane)*8] holds W[p=P*16+(lane&15)][k=ks*32+(lane>>4)*8 .. +8]
// blocks 32..47: msg[b][h] -> msgTT[(h>>2)*4096 + b*4 + (h&3)]  (float4-per-(b,hgroup))
__global__ __launch_bounds__(256) void k_fmt(
    const float* __restrict__ w1, const float* __restrict__ w2,
    const float* __restrict__ w3, const float* __restrict__ msg,
    short* __restrict__ wf, float* __restrict__ msgTT) {
  __shared__ float T[64][257];
  const int t = threadIdx.x;
  if (blockIdx.x < 32) {
    int u = blockIdx.x * 256 + t;              // 0..8191
    const float* src; short* dst; int row, c, Kt;
    if (u < 4096)      { src = w1; dst = wf;          Kt = 8; row = u >> 5; c = u & 31; }
    else if (u < 6144) { src = w2; dst = wf + 32768;  Kt = 4; row = (u-4096) >> 4; c = (u-4096) & 15; }
    else               { src = w3; dst = wf + 49152;  Kt = 4; row = (u-6144) >> 4; c = (u-6144) & 15; }
    int ks = c >> 2, q = c & 3, Kd = Kt * 32;
    const float* s = src + row * Kd + ks * 32 + q * 8;     // coalesced 32B/thread
    float4 a = *(const float4*)s, b = *(const float4*)(s + 4);
    int P = row >> 4, r16 = row & 15;
    int outl = ((P * Kt + ks) * 64 + q * 16 + r16);
    *(uint4*)(dst + (size_t)outl * 8) = pack8u(a, b);
  } else {
    const int b0 = (blockIdx.x - 32) * 64;
    #pragma unroll 4
    for (int it = 0; it < 16; ++it) {
      int flat = it * 1024 + t * 4;
      int row = flat >> 8, col = flat & 255;
      float4 v = *(const float4*)(msg + (b0 + row) * HDIM + col);
      T[row][col] = v.x; T[row][col+1] = v.y; T[row][col+2] = v.z; T[row][col+3] = v.w;
    }
    __syncthreads();
    const int bloc = t & 63;
    #pragma unroll 4
    for (int it = 0; it < 16; ++it) {
      int g = it * 4 + (t >> 6);
      float4 v; v.x = T[bloc][g*4]; v.y = T[bloc][g*4+1];
                v.z = T[bloc][g*4+2]; v.w = T[bloc][g*4+3];
      *(float4*)(msgTT + (size_t)g * 4096 + (b0 + bloc) * 4) = v;
    }
  }
}

// ---------------- Kernel 1: front MLP -> x3 fragments ---------------------
// 64 blocks x 16 b. Weight fragments loaded coalesced global->VGPR (no
// weight LDS, no staging barriers). Activations ping-pong via small LDS.
// Output x3f in B-fragment order: x3f[((Bt*4 + ks)*64 + lane)*8].
__global__ __launch_bounds__(256) void k_mlp(
    const float* __restrict__ h0, const float* __restrict__ htv,
    const float* __restrict__ cp, const short* __restrict__ wf,
    short* __restrict__ x3f) {
  __shared__ char hbuf[8192];    // 16 x 256 bf16, swizzled 16B blocks
  __shared__ char xa[4096];      // 16 x 128 bf16, swizzled
  __shared__ char xb[4096];
  const int t = threadIdx.x, wave = t >> 6, lane = t & 63;
  const int r16 = lane & 15, quad = lane >> 4;
  const int b0 = blockIdx.x * 16;
  const float cc = fminf(fmaxf(cp[0], 0.f), 1.f);

  // stage h = cc*h0+(1-cc)*ht (16x256)
  #pragma unroll
  for (int it = 0; it < 2; ++it) {
    int flat = it * 2048 + t * 8;
    int row = flat >> 8, col = flat & 255, kb = col >> 3;
    int gi = (b0 + row) * HDIM + col;
    float4 a = *(const float4*)(h0 + gi);
    float4 b = *(const float4*)(htv + gi);
    float4 va, vb;
    va.x = cc*a.x + (1.f-cc)*b.x; va.y = cc*a.y + (1.f-cc)*b.y;
    va.z = cc*a.z + (1.f-cc)*b.z; va.w = cc*a.w + (1.f-cc)*b.w;
    a = *(const float4*)(h0 + gi + 4); b = *(const float4*)(htv + gi + 4);
    vb.x = cc*a.x + (1.f-cc)*b.x; vb.y = cc*a.y + (1.f-cc)*b.y;
    vb.z = cc*a.z + (1.f-cc)*b.z; vb.w = cc*a.w + (1.f-cc)*b.w;
    *(uint4*)(hbuf + row*512 + ((kb ^ (row & 7)) << 4)) = pack8u(va, vb);
  }
  __syncthreads();

  // layer 1: [16 x 256] @ w1^T -> xa
  {
    f32x4 acc[2] = {};
    #pragma unroll
    for (int ks = 0; ks < 8; ++ks) {
      bf8 af = *(bf8*)(hbuf + r16*512 + (((ks*4 + quad) ^ (r16 & 7)) << 4));
      #pragma unroll
      for (int nt = 0; nt < 2; ++nt) {
        bf8 bw_ = *(const bf8*)(wf + (size_t)(((wave*2 + nt)*8 + ks)*64 + lane)*8);
        acc[nt] = __builtin_amdgcn_mfma_f32_16x16x32_bf16(af, bw_, acc[nt], 0, 0, 0);
      }
    }
    #pragma unroll
    for (int nt = 0; nt < 2; ++nt)
      #pragma unroll
      for (int i = 0; i < 4; ++i) {
        int row = quad*4 + i, col = wave*32 + nt*16 + r16;
        *(unsigned short*)(xa + row*256 + (((col >> 3) ^ (row & 7)) << 4) + ((col & 7) << 1))
            = bfbits(fast_tanh(acc[nt][i]));
      }
  }
  __syncthreads();
  // layer 2: xa @ w2^T -> xb
  {
    f32x4 acc[2] = {};
    #pragma unroll
    for (int ks = 0; ks < 4; ++ks) {
      bf8 af = *(bf8*)(xa + r16*256 + (((ks*4 + quad) ^ (r16 & 7)) << 4));
      #pragma unroll
      for (int nt = 0; nt < 2; ++nt) {
        bf8 bw_ = *(const bf8*)(wf + 32768 + (size_t)(((wave*2 + nt)*4 + ks)*64 + lane)*8);
        acc[nt] = __builtin_amdgcn_mfma_f32_16x16x32_bf16(af, bw_, acc[nt], 0, 0, 0);
      }
    }
    #pragma unroll
    for (int nt = 0; nt < 2; ++nt)
      #pragma unroll
      for (int i = 0; i < 4; ++i) {
        int row = quad*4 + i, col = wave*32 + nt*16 + r16;
        *(unsigned short*)(xb + row*256 + (((col >> 3) ^ (row & 7)) << 4) + ((col & 7) << 1))
            = bfbits(fast_tanh(acc[nt][i]));
      }
  }
  __syncthreads();
  // layer 3: xb @ w3^T -> xa
  {
    f32x4 acc[2] = {};
    #pragma unroll
    for (int ks = 0; ks < 4; ++ks) {
      bf8 af = *(bf8*)(xb + r16*256 + (((ks*4 + quad) ^ (r16 & 7)) << 4));
      #pragma unroll
      for (int nt = 0; nt < 2; ++nt) {
        bf8 bw_ = *(const bf8*)(wf + 49152 + (size_t)(((wave*2 + nt)*4 + ks)*64 + lane)*8);
        acc[nt] = __builtin_amdgcn_mfma_f32_16x16x32_bf16(af, bw_, acc[nt], 0, 0, 0);
      }
    }
    #pragma unroll
    for (int nt = 0; nt < 2; ++nt)
      #pragma unroll
      for (int i = 0; i < 4; ++i) {
        int row = quad*4 + i, col = wave*32 + nt*16 + r16;
        *(unsigned short*)(xa + row*256 + (((col >> 3) ^ (row & 7)) << 4) + ((col & 7) << 1))
            = bfbits(fast_tanh(acc[nt][i]));
      }
  }
  __syncthreads();
  // dump xa -> x3f in B-fragment order (coalesced uint4 per lane)
  {
    int ks = t >> 6, l = t & 63, q2 = l >> 4, rr = l & 15;
    uint4 d = *(uint4*)(xa + rr*256 + (((ks*4 + q2) ^ (rr & 7)) << 4));
    *(uint4*)(x3f + (size_t)((blockIdx.x*4 + ks)*64 + l)*8) = d;
  }
}

// ---------------- Kernel 2/3: fused hypernetwork GEMM --------------------
// PHASE 0: g1TT[k,b] = tanh( sum_h msgTT[h,b] * (fc4[kcol*256+h,:] . x3[b,:]) )
// PHASE 1: out[b,kcol] =     sum_k g1TT[k,b]  * (fc4[65536+kcol*256+k,:] . x3[b,:])
// Grid (256 kcol, 4 y); block = 256 b, wave owns 64 b. Slab staged in two
// 128-row halves (32 KB LDS, 4 blocks/CU). wvec = one dwordx4 per (ht,nt).
template<int PHASE>
__global__ __launch_bounds__(256, 4) void k_hyper(
    const short* __restrict__ x3f, const float* __restrict__ wTT,
    const float* __restrict__ fc4, float* __restrict__ outp) {
  __shared__ char lds[32768];          // 128 rows x 128 bf16, xor-swizzled
  const int kcol = blockIdx.x;
  const int t = threadIdx.x, wave = t >> 6, lane = t & 63;
  const int r16 = lane & 15, quad = lane >> 4;
  const int bw = blockIdx.y * 256 + wave * 64;

  // x3 B-fragments (coalesced 1KB b128 wave-loads), held whole kernel
  bf8 xf[4][4];
  #pragma unroll
  for (int nt = 0; nt < 4; ++nt)
    #pragma unroll
    for (int ks = 0; ks < 4; ++ks)
      xf[nt][ks] = *(const bf8*)(x3f +
          (size_t)(((blockIdx.y*16 + wave*4 + nt)*4 + ks)*64 + lane)*8);

  const float* src = fc4 + ((size_t)(PHASE ? 65536 : 0) + (size_t)kcol * 256) * HPDIM;
  float gacc[4] = {0.f, 0.f, 0.f, 0.f};

  #pragma unroll 1
  for (int half = 0; half < 2; ++half) {
    // stage 128 rows x 128 f32 -> bf16 LDS
    #pragma unroll
    for (int it = 0; it < 8; ++it) {
      int flat = it * 2048 + t * 8;
      int row = flat >> 7, kb = t & 15;
      float4 a = *(const float4*)(src + half*16384 + flat);
      float4 b = *(const float4*)(src + half*16384 + flat + 4);
      *(uint4*)(lds + row*256 + ((kb ^ (row & 7)) << 4)) = pack8u(a, b);
    }
    __syncthreads();

    #pragma unroll 2
    for (int ht = 0; ht < 8; ++ht) {
      // weight vectors first (independent dwordx4, hide latency under MFMA)
      const int hb = half*32 + ht*4 + quad;          // h-group (h>>2)
      float4 wv[4];
      #pragma unroll
      for (int nt = 0; nt < 4; ++nt)
        wv[nt] = *(const float4*)(wTT + (size_t)hb*4096 + (bw + nt*16 + r16)*4);
      const int row = ht*16 + r16;
      bf8 af[4];
      #pragma unroll
      for (int ks = 0; ks < 4; ++ks)
        af[ks] = *(bf8*)(lds + row*256 + (((ks*4 + quad) ^ (row & 7)) << 4));
      #pragma unroll
      for (int nt = 0; nt < 4; ++nt) {
        f32x4 acc = {};
        #pragma unroll
        for (int ks = 0; ks < 4; ++ks)
          acc = __builtin_amdgcn_mfma_f32_16x16x32_bf16(af[ks], xf[nt][ks], acc, 0, 0, 0);
        gacc[nt] += acc[0]*wv[nt].x + acc[1]*wv[nt].y + acc[2]*wv[nt].z + acc[3]*wv[nt].w;
      }
    }
    __syncthreads();                         // slab reads done before restage
  }

  #pragma unroll
  for (int nt = 0; nt < 4; ++nt) {
    float v = gacc[nt];
    v += __shfl_xor(v, 16);
    v += __shfl_xor(v, 32);
    if (quad == 0) {
      int b = bw + nt*16 + r16;
      if (PHASE == 0) outp[(size_t)(kcol >> 2)*4096 + b*4 + (kcol & 3)] = fast_tanh(v);
      else            outp[b*HDIM + kcol] = v;
    }
  }
}

extern "C" void kernel_launch(void* const* d_in, const int* in_sizes, int n_in,
                              void* d_out, int out_size, void* d_ws, size_t ws_size,
                              hipStream_t stream) {
  const float* h0  = (const float*)d_in[0];
  const float* htt = (const float*)d_in[1];
  const float* msg = (const float*)d_in[2];
  const float* c   = (const float*)d_in[3];
  const float* w1  = (const float*)d_in[4];
  const float* w2  = (const float*)d_in[5];
  const float* w3  = (const float*)d_in[6];
  const float* w4  = (const float*)d_in[7];
  float* out = (float*)d_out;

  short* x3f  = (short*)d_ws;                              // 256 KB
  float* g1TT = (float*)((char*)d_ws + 262144);            // 1 MB
  float* msgTT= (float*)((char*)d_ws + 262144 + 1048576);  // 1 MB
  short* wf   = (short*)((char*)d_ws + 262144 + 2097152);  // 128 KB

  k_fmt<<<dim3(48), dim3(256), 0, stream>>>(w1, w2, w3, msg, wf, msgTT);
  k_mlp<<<dim3(64), dim3(256), 0, stream>>>(h0, htt, c, wf, x3f);
  k_hyper<0><<<dim3(256, 4), dim3(256), 0, stream>>>(x3f, msgTT, w4, g1TT);
  k_hyper<1><<<dim3(256, 4), dim3(256), 0, stream>>>(x3f, g1TT, w4, out);
}